// Round 8
// baseline (370.835 us; speedup 1.0000x reference)
//
#include <hip/hip_runtime.h>
#include <hip/hip_bf16.h>
#include <math.h>

typedef __hip_bfloat16 bf16;
typedef __bf16 bf16x8 __attribute__((ext_vector_type(8)));
typedef float f32x4 __attribute__((ext_vector_type(4)));
typedef float f32x4v __attribute__((ext_vector_type(4)));
typedef unsigned short u16x8v __attribute__((ext_vector_type(8)));
typedef unsigned short u16x4v __attribute__((ext_vector_type(4)));

#define AS1 __attribute__((address_space(1)))
#define AS3 __attribute__((address_space(3)))

// Problem constants
#define BB 4
#define TT 4096
#define DD 1024

__device__ __forceinline__ float fast_sigmoid(float x) {
  return 1.0f / (1.0f + __expf(-x));
}
__device__ __forceinline__ float fast_tanh(float x) {
  return 2.0f / (1.0f + __expf(-2.0f * x)) - 1.0f;
}
__device__ __forceinline__ float b2f(unsigned short u) {
  union { unsigned int i; float f; } x;
  x.i = ((unsigned int)u) << 16;
  return x.f;
}
__device__ __forceinline__ unsigned short f2b(float f) {
  union { bf16 h; unsigned short u; } x;
  x.h = __float2bfloat16(f);
  return x.u;
}

// ---------------------------------------------------------------------------
// Weight fp32 -> bf16
// ---------------------------------------------------------------------------
__global__ __launch_bounds__(256) void w2bf_kernel(const float* __restrict__ w,
                                                   bf16* __restrict__ o,
                                                   int n) {
  int i = blockIdx.x * 256 + threadIdx.x;
  if (i < n) o[i] = __float2bfloat16(w[i]);
}

// ---------------------------------------------------------------------------
// conv + add -> bf16, 4 channels / thread
// ---------------------------------------------------------------------------
__global__ __launch_bounds__(256) void conv_add_kernel(
    const float* __restrict__ x, const float* __restrict__ Wc,
    bf16* __restrict__ xm, int total4) {
  int i = blockIdx.x * 256 + threadIdx.x;
  if (i >= total4) return;
  int c4 = (i & (DD / 4 - 1)) * 4;
  int t = (i / (DD / 4)) % TT;
  size_t base = (size_t)i * 4;
  f32x4v x0 = *(const f32x4v*)(x + base);
  f32x4v p1 = (t >= 1) ? *(const f32x4v*)(x + base - DD) : (f32x4v)0.0f;
  f32x4v p2 = (t >= 2) ? *(const f32x4v*)(x + base - 2 * DD) : (f32x4v)0.0f;
  f32x4v p3 = (t >= 3) ? *(const f32x4v*)(x + base - 3 * DD) : (f32x4v)0.0f;
  u16x4v o;
#pragma unroll
  for (int j = 0; j < 4; ++j) {
    f32x4v w = *(const f32x4v*)(Wc + (size_t)(c4 + j) * 4);
    float acc = x0[j] + w[3] * x0[j] + w[2] * p1[j] + w[1] * p2[j] +
                w[0] * p3[j];
    o[j] = f2b(acc);
  }
  *(u16x4v*)(xm + base) = o;
}

// ---------------------------------------------------------------------------
// 128x128 MFMA GEMM, BK=64, 4 waves (2Mx2N), SINGLE-buffered 32 KiB LDS,
// m97-exact 2-barrier loop, NO manual scheduling (compiler-scheduled; m141:
// order-pinning hurts). Cross-WG overlap (>=3 WG/CU) hides the barrier
// drain (m114). C[m][n] = sum_k A[m][k]*B[n][k]; bf16 A,B; K%64==0,
// M,N%128==0, MB%8==0.
// LDS rows are 64 elems = 128 B = 8 x 16B slots -> full 8-way XOR swizzle
// (r5-verified involution, 0 conflicts):
//   staged: lane l of wave-load j writes row (l>>3), phys slot (l&7);
//           global source pre-swizzled: logical slot = (l&7) ^ (l>>3)
//   read: logical slot ks*4+(l>>4); phys = logical ^ (row&7), row&7 = l15&7
// EP=0: fp32 C. EP=1: bf16 C with per-1024-col activation.
// ---------------------------------------------------------------------------
template <int EP>
__global__ __launch_bounds__(256) void gemm128_kernel(
    const bf16* __restrict__ A, const bf16* __restrict__ B,
    void* __restrict__ C, int M, int N, int K, int MB) {
  __shared__ __align__(16) bf16 As[128][64];
  __shared__ __align__(16) bf16 Bs[128][64];

  const int tid = threadIdx.x;
  const int wv = tid >> 6, l = tid & 63;
  const int wm = wv >> 1, wn = wv & 1;

  // XCD-chunked bijective block mapping
  const int bid = blockIdx.x;
  const int xcd = bid & 7, ii = bid >> 3;
  const int mb8 = MB >> 3;
  const int bm = xcd * mb8 + (ii % mb8);
  const int bn = ii / mb8;
  const int m0 = bm * 128, n0 = bn * 128;

  // staging source (pre-swizzled)
  const int lr3 = l >> 3;
  const int scolE = ((l & 7) ^ lr3) * 8;
  const bf16* Ab = A + (size_t)(m0 + wv * 32 + lr3) * K + scolE;
  const bf16* Bb = B + (size_t)(n0 + wv * 32 + lr3) * K + scolE;

  // frag-read constants
  const int l15 = l & 15;
  const int lh = l >> 4;  // 0..3 (logical slot within k-slice)
  const char* AsB = (const char*)As;
  const char* BsB = (const char*)Bs;

  f32x4 acc[4][4];
#pragma unroll
  for (int i = 0; i < 4; ++i)
#pragma unroll
    for (int j = 0; j < 4; ++j) acc[i][j] = (f32x4)0.0f;

  const int NT = K >> 6;

#pragma unroll 1
  for (int kt = 0; kt < NT; ++kt) {
    const int k0 = kt * 64;
    // stage K-tile (8 x global_load_lds per wave)
#pragma unroll
    for (int j = 0; j < 4; ++j) {
      __builtin_amdgcn_global_load_lds(
          (const AS1 void*)(Ab + (size_t)(j * 8) * K + k0),
          (AS3 void*)&As[wv * 32 + j * 8][0], 16, 0, 0);
      __builtin_amdgcn_global_load_lds(
          (const AS1 void*)(Bb + (size_t)(j * 8) * K + k0),
          (AS3 void*)&Bs[wv * 32 + j * 8][0], 16, 0, 0);
    }
    __syncthreads();  // drains vmcnt: tile resident

    bf16x8 aF[4][2], bF[4][2];
#pragma unroll
    for (int mi = 0; mi < 4; ++mi) {
      const int row = wm * 64 + mi * 16 + l15;
#pragma unroll
      for (int ks = 0; ks < 2; ++ks) {
        const int ps = (ks * 4 + lh) ^ (l15 & 7);
        aF[mi][ks] = *(const bf16x8*)(AsB + row * 128 + ps * 16);
      }
    }
#pragma unroll
    for (int nj = 0; nj < 4; ++nj) {
      const int row = wn * 64 + nj * 16 + l15;
#pragma unroll
      for (int ks = 0; ks < 2; ++ks) {
        const int ps = (ks * 4 + lh) ^ (l15 & 7);
        bF[nj][ks] = *(const bf16x8*)(BsB + row * 128 + ps * 16);
      }
    }
#pragma unroll
    for (int ks = 0; ks < 2; ++ks)
#pragma unroll
      for (int mi = 0; mi < 4; ++mi)
#pragma unroll
        for (int nj = 0; nj < 4; ++nj)
          acc[mi][nj] = __builtin_amdgcn_mfma_f32_16x16x32_bf16(
              aF[mi][ks], bF[nj][ks], acc[mi][nj], 0, 0, 0);
    __syncthreads();  // all reads done before next stage overwrites
  }

  // epilogue: C/D layout col=lane&15, row=(lane>>4)*4+j
#pragma unroll
  for (int mi = 0; mi < 4; ++mi) {
    const int row = m0 + wm * 64 + mi * 16 + (l >> 4) * 4;
#pragma unroll
    for (int nj = 0; nj < 4; ++nj) {
      const int col = n0 + wn * 64 + nj * 16 + l15;
#pragma unroll
      for (int j = 0; j < 4; ++j) {
        float v = acc[mi][nj][j];
        if (EP == 0) {
          ((float*)C)[(size_t)(row + j) * N + col] = v;
        } else {
          const int cls = col >> 10;
          if (cls == 1 || cls == 2) v = fast_sigmoid(v);
          else if (cls == 3) v = fast_tanh(v);
          ((bf16*)C)[(size_t)(row + j) * N + col] = __float2bfloat16(v);
        }
      }
    }
  }
}

// ---------------------------------------------------------------------------
// Fallback fp32-B GEMM (tier-3 out-proj only)
// ---------------------------------------------------------------------------
#define BM 64
#define BN 64
#define BKK 16
__global__ __launch_bounds__(256) void gemm_nt_kernel(
    const bf16* __restrict__ A, const float* __restrict__ B,
    float* __restrict__ C, int M, int N, int K) {
  __shared__ float Asm[BKK][BM + 1];
  __shared__ float Bsm[BKK][BN + 1];
  const int n0 = blockIdx.x * BN;
  const int m0 = blockIdx.y * BM;
  const int tid = threadIdx.x;
  const int tx = tid & 15, ty = tid >> 4;
  const int lk = tid & 15, lr = tid >> 4;
  float acc[4][4] = {};
  for (int k0 = 0; k0 < K; k0 += BKK) {
#pragma unroll
    for (int p = 0; p < 4; ++p) {
      Asm[lk][lr + 16 * p] =
          __bfloat162float(A[(size_t)(m0 + lr + 16 * p) * K + (k0 + lk)]);
      Bsm[lk][lr + 16 * p] = B[(size_t)(n0 + lr + 16 * p) * K + (k0 + lk)];
    }
    __syncthreads();
#pragma unroll
    for (int kk = 0; kk < BKK; ++kk) {
      float a[4], b[4];
#pragma unroll
      for (int i = 0; i < 4; ++i) a[i] = Asm[kk][ty * 4 + i];
#pragma unroll
      for (int j = 0; j < 4; ++j) b[j] = Bsm[kk][tx * 4 + j];
#pragma unroll
      for (int i = 0; i < 4; ++i)
#pragma unroll
        for (int j = 0; j < 4; ++j) acc[i][j] += a[i] * b[j];
    }
    __syncthreads();
  }
#pragma unroll
  for (int i = 0; i < 4; ++i)
#pragma unroll
    for (int j = 0; j < 4; ++j)
      C[(size_t)(m0 + ty * 4 + i) * N + (n0 + tx * 4 + j)] = acc[i][j];
}

// ---------------------------------------------------------------------------
// Chunked scan, 8 channels/thread (16B bf16 loads)
// ---------------------------------------------------------------------------
__global__ __launch_bounds__(256) void scan_chunk_kernel(
    const bf16* __restrict__ u, float* __restrict__ cA,
    float* __restrict__ cB, int nchunk, int tchunk) {
  int idx = blockIdx.x * 256 + threadIdx.x;
  int c8 = (idx & (DD / 8 - 1)) * 8;
  int chunk = (idx / (DD / 8)) % nchunk;
  int b = idx / ((DD / 8) * nchunk);
  const bf16* ub = u + (size_t)b * TT * 4 * DD;
  float Aacc[8], Bacc[8];
#pragma unroll
  for (int j = 0; j < 8; ++j) { Aacc[j] = 1.0f; Bacc[j] = 0.0f; }
  int t0 = chunk * tchunk;
  for (int t = t0; t < t0 + tchunk; ++t) {
    const bf16* row = ub + (size_t)t * 4 * DD;
    u16x8v dv = *(const u16x8v*)(row + 2 * DD + c8);
    u16x8v iv = *(const u16x8v*)(row + 3 * DD + c8);
#pragma unroll
    for (int j = 0; j < 8; ++j) {
      float dec = b2f(dv[j]), inj = b2f(iv[j]);
      Aacc[j] *= dec;
      Bacc[j] = dec * Bacc[j] + (1.0f - dec) * inj;
    }
  }
  int base = (b * nchunk + chunk) * DD + c8;
#pragma unroll
  for (int j = 0; j < 8; ++j) { cA[base + j] = Aacc[j]; cB[base + j] = Bacc[j]; }
}

__global__ __launch_bounds__(256) void scan_prefix_kernel(
    const float* __restrict__ cA, const float* __restrict__ cB,
    float* __restrict__ S, int nchunk) {
  int idx = blockIdx.x * 256 + threadIdx.x;
  int c = idx % DD;
  int b = idx / DD;
  float s = 0.0f;
  for (int j = 0; j < nchunk; ++j) {
    int e = (b * nchunk + j) * DD + c;
    S[e] = s;
    s = cA[e] * s + cB[e];
  }
}

__global__ __launch_bounds__(256) void scan_out_kernel(
    const bf16* __restrict__ u, const float* __restrict__ S,
    bf16* __restrict__ y, int nchunk, int tchunk) {
  int idx = blockIdx.x * 256 + threadIdx.x;
  int c8 = (idx & (DD / 8 - 1)) * 8;
  int chunk = (idx / (DD / 8)) % nchunk;
  int b = idx / ((DD / 8) * nchunk);
  const bf16* ub = u + (size_t)b * TT * 4 * DD;
  bf16* yb = y + (size_t)b * TT * DD;
  float st[8];
  int sbase = (b * nchunk + chunk) * DD + c8;
#pragma unroll
  for (int j = 0; j < 8; ++j) st[j] = S[sbase + j];
  int t0 = chunk * tchunk;
  for (int t = t0; t < t0 + tchunk; ++t) {
    const bf16* row = ub + (size_t)t * 4 * DD;
    u16x8v vv = *(const u16x8v*)(row + c8);
    u16x8v gv = *(const u16x8v*)(row + DD + c8);
    u16x8v dv = *(const u16x8v*)(row + 2 * DD + c8);
    u16x8v iv = *(const u16x8v*)(row + 3 * DD + c8);
    u16x8v ov;
#pragma unroll
    for (int j = 0; j < 8; ++j) {
      float dec = b2f(dv[j]), inj = b2f(iv[j]);
      float g = b2f(gv[j]), v = b2f(vv[j]);
      st[j] = dec * st[j] + (1.0f - dec) * inj;
      ov[j] = f2b(g * v + (1.0f - g) * st[j]);
    }
    *(u16x8v*)(yb + (size_t)t * DD + c8) = ov;
  }
}

// ---------------------------------------------------------------------------
extern "C" void kernel_launch(void* const* d_in, const int* in_sizes, int n_in,
                              void* d_out, int out_size, void* d_ws,
                              size_t ws_size, hipStream_t stream) {
  const float* x = (const float*)d_in[0];
  const float* Wc = (const float*)d_in[1];
  const float* Wp = (const float*)d_in[2];
  const float* Wo = (const float*)d_in[3];
  float* out = (float*)d_out;

  const size_t nb = (size_t)TT * DD;

  auto need = [&](int nbat, int nchunk, bool wob) -> size_t {
    return (size_t)nbat * nb * 2 + (size_t)nbat * 4 * nb * 2 +
           (size_t)4 * DD * DD * 2 + (wob ? (size_t)DD * DD * 2 : 0) +
           (size_t)3 * nbat * nchunk * DD * 4;
  };

  int nbat, nchunk;
  bool haveWob;
  if (ws_size >= need(4, 64, true)) {
    nbat = 4; nchunk = 64; haveWob = true;
  } else if (ws_size >= need(1, 64, true)) {
    nbat = 1; nchunk = 64; haveWob = true;
  } else {
    nbat = 1; nchunk = 16; haveWob = false;
  }
  const int tchunk = TT / nchunk;

  char* p = (char*)d_ws;
  bf16* Wpb = (bf16*)p;  p += (size_t)4 * DD * DD * 2;
  bf16* Wob = nullptr;
  if (haveWob) { Wob = (bf16*)p; p += (size_t)DD * DD * 2; }
  bf16* xm = (bf16*)p;   p += (size_t)nbat * nb * 2;  // also y
  bf16* u = (bf16*)p;    p += (size_t)nbat * 4 * nb * 2;
  float* cA = (float*)p; p += (size_t)nbat * nchunk * DD * 4;
  float* cB = (float*)p; p += (size_t)nbat * nchunk * DD * 4;
  float* S = (float*)p;
  bf16* y = xm;

  w2bf_kernel<<<(4 * DD * DD) / 256, 256, 0, stream>>>(Wp, Wpb, 4 * DD * DD);
  if (haveWob)
    w2bf_kernel<<<(DD * DD) / 256, 256, 0, stream>>>(Wo, Wob, DD * DD);

  for (int b0 = 0; b0 < BB; b0 += nbat) {
    const float* xb = x + (size_t)b0 * nb;
    float* outb = out + (size_t)b0 * nb;
    const int Mtot = nbat * TT;
    const int total4 = (int)(nbat * nb / 4);

    conv_add_kernel<<<total4 / 256, 256, 0, stream>>>(xb, Wc, xm, total4);

    {  // u = act(xm @ Wp^T): M=Mtot, N=4096, K=1024
      const int MB = Mtot / 128;
      const int nwg = MB * (4 * DD / 128);
      gemm128_kernel<1><<<nwg, 256, 0, stream>>>(xm, Wpb, u, Mtot, 4 * DD, DD,
                                                 MB);
    }
    {
      int nthreads = nbat * nchunk * (DD / 8);
      scan_chunk_kernel<<<nthreads / 256, 256, 0, stream>>>(u, cA, cB, nchunk,
                                                            tchunk);
      scan_prefix_kernel<<<(nbat * DD) / 256, 256, 0, stream>>>(cA, cB, S,
                                                                nchunk);
      scan_out_kernel<<<nthreads / 256, 256, 0, stream>>>(u, S, y, nchunk,
                                                          tchunk);
    }
    if (haveWob) {  // out = y @ Wo^T: M=Mtot, N=1024, K=1024
      const int MB = Mtot / 128;
      const int nwg = MB * (DD / 128);
      gemm128_kernel<0><<<nwg, 256, 0, stream>>>(y, Wob, outb, Mtot, DD, DD,
                                                 MB);
    } else {
      dim3 grid(DD / BN, Mtot / BM);
      gemm_nt_kernel<<<grid, 256, 0, stream>>>(y, Wo, outb, Mtot, DD, DD);
    }
  }
}

// Round 9
// 370.481 us; speedup vs baseline: 1.0010x; 1.0010x over previous
//
#include <hip/hip_runtime.h>
#include <hip/hip_bf16.h>
#include <math.h>

typedef __hip_bfloat16 bf16;
typedef __bf16 bf16x8 __attribute__((ext_vector_type(8)));
typedef float f32x4 __attribute__((ext_vector_type(4)));
typedef float f32x4v __attribute__((ext_vector_type(4)));
typedef unsigned short u16x8v __attribute__((ext_vector_type(8)));
typedef unsigned short u16x4v __attribute__((ext_vector_type(4)));

#define AS1 __attribute__((address_space(1)))
#define AS3 __attribute__((address_space(3)))

// Problem constants
#define BB 4
#define TT 4096
#define DD 1024

__device__ __forceinline__ float fast_sigmoid(float x) {
  return 1.0f / (1.0f + __expf(-x));
}
__device__ __forceinline__ float fast_tanh(float x) {
  return 2.0f / (1.0f + __expf(-2.0f * x)) - 1.0f;
}
__device__ __forceinline__ float b2f(unsigned short u) {
  union { unsigned int i; float f; } x;
  x.i = ((unsigned int)u) << 16;
  return x.f;
}
__device__ __forceinline__ unsigned short f2b(float f) {
  union { bf16 h; unsigned short u; } x;
  x.h = __float2bfloat16(f);
  return x.u;
}

// ---------------------------------------------------------------------------
// Weight fp32 -> bf16
// ---------------------------------------------------------------------------
__global__ __launch_bounds__(256) void w2bf_kernel(const float* __restrict__ w,
                                                   bf16* __restrict__ o,
                                                   int n) {
  int i = blockIdx.x * 256 + threadIdx.x;
  if (i < n) o[i] = __float2bfloat16(w[i]);
}

// ---------------------------------------------------------------------------
// conv + add -> bf16, 4 channels / thread
// ---------------------------------------------------------------------------
__global__ __launch_bounds__(256) void conv_add_kernel(
    const float* __restrict__ x, const float* __restrict__ Wc,
    bf16* __restrict__ xm, int total4) {
  int i = blockIdx.x * 256 + threadIdx.x;
  if (i >= total4) return;
  int c4 = (i & (DD / 4 - 1)) * 4;
  int t = (i / (DD / 4)) % TT;
  size_t base = (size_t)i * 4;
  f32x4v x0 = *(const f32x4v*)(x + base);
  f32x4v p1 = (t >= 1) ? *(const f32x4v*)(x + base - DD) : (f32x4v)0.0f;
  f32x4v p2 = (t >= 2) ? *(const f32x4v*)(x + base - 2 * DD) : (f32x4v)0.0f;
  f32x4v p3 = (t >= 3) ? *(const f32x4v*)(x + base - 3 * DD) : (f32x4v)0.0f;
  u16x4v o;
#pragma unroll
  for (int j = 0; j < 4; ++j) {
    f32x4v w = *(const f32x4v*)(Wc + (size_t)(c4 + j) * 4);
    float acc = x0[j] + w[3] * x0[j] + w[2] * p1[j] + w[1] * p2[j] +
                w[0] * p3[j];
    o[j] = f2b(acc);
  }
  *(u16x4v*)(xm + base) = o;
}

// ---------------------------------------------------------------------------
// 128x128 MFMA GEMM, BK=32, 4 waves (2Mx2N), TRIPLE-buffered 48 KiB LDS
// (3 WG/CU), lead-2 staging, vmcnt(4) gates, ONE barrier per phase.
// Phase p: {stage(p+2) -> buf[(p+2)%3] (4 gll) | 8 ds_read from buf[p%3]
// (compiler-interleaved lgkmcnt with MFMA) | 16 MFMA | vmcnt gate | barrier}.
// Hazards: reads of buf[p] gated by previous phase's vmcnt(4)+barrier;
// stage(p+2) never touches buf[p] or buf[p+1]; the end barrier separates
// phase p-1's reads of buf[(p-1)%3] from phase p+1's overwrite of it.
// C[m][n] = sum_k A[m][k]*B[n][k]; bf16; K%64==0, M,N%128==0, MB%8==0.
// LDS swizzle (r7-verified involution, 4 slots of 8 elems per 32-elem row):
//   staged: lane l -> row l>>2, phys slot l&3; source logical slot
//           (l&3)^((l>>2)&3); read phys = (l>>4) ^ (l15&3).
// EP=0: fp32 C. EP=1: bf16 C with per-1024-col activation.
// ---------------------------------------------------------------------------
template <int EP>
__global__ __launch_bounds__(256, 3) void gemm128_kernel(
    const bf16* __restrict__ A, const bf16* __restrict__ B,
    void* __restrict__ C, int M, int N, int K, int MB) {
  __shared__ __align__(16) bf16 As[3][128][32];
  __shared__ __align__(16) bf16 Bs[3][128][32];

  const int tid = threadIdx.x;
  const int wv = tid >> 6, l = tid & 63;
  const int wm = wv >> 1, wn = wv & 1;

  // XCD-chunked bijective block mapping
  const int bid = blockIdx.x;
  const int xcd = bid & 7, ii = bid >> 3;
  const int mb8 = MB >> 3;
  const int bm = xcd * mb8 + (ii % mb8);
  const int bn = ii / mb8;
  const int m0 = bm * 128, n0 = bn * 128;

  // staging source (pre-swizzled)
  const int srow = l >> 2;
  const int scolE = ((l & 3) ^ ((l >> 2) & 3)) * 8;
  const bf16* Ab = A + (size_t)(m0 + wv * 32 + srow) * K + scolE;
  const bf16* Bb = B + (size_t)(n0 + wv * 32 + srow) * K + scolE;

  // frag-read constants
  const int l15 = l & 15;
  const int physColB = ((l >> 4) ^ (l & 3)) * 16;
  const char* AsB = (const char*)As;
  const char* BsB = (const char*)Bs;
  const int aBase = wm * 4096 + l15 * 64 + physColB;
  const int bBase = wn * 4096 + l15 * 64 + physColB;

  // stage K-tile kt into LDS buffer slot (4 gll per wave)
  auto stageKt = [&](int kt, int slot) {
    const int k0 = kt * 32;
#pragma unroll
    for (int j = 0; j < 2; ++j) {
      __builtin_amdgcn_global_load_lds(
          (const AS1 void*)(Ab + (size_t)(j * 16) * K + k0),
          (AS3 void*)&As[slot][wv * 32 + j * 16][0], 16, 0, 0);
      __builtin_amdgcn_global_load_lds(
          (const AS1 void*)(Bb + (size_t)(j * 16) * K + k0),
          (AS3 void*)&Bs[slot][wv * 32 + j * 16][0], 16, 0, 0);
    }
  };

  f32x4 acc[4][4];
#pragma unroll
  for (int i = 0; i < 4; ++i)
#pragma unroll
    for (int j = 0; j < 4; ++j) acc[i][j] = (f32x4)0.0f;

  const int NT = K >> 5;

  // prologue: stage kt0 -> buf0, kt1 -> buf1; wait kt0; barrier
  stageKt(0, 0);
  stageKt(1, 1);
  asm volatile("s_waitcnt vmcnt(4)" ::: "memory");
  __builtin_amdgcn_sched_barrier(0);
  __builtin_amdgcn_s_barrier();

  bf16x8 aF[4], bF[4];
  int cur = 0;

#pragma unroll 1
  for (int p = 0; p < NT; ++p) {
    // stage(p+2) into buf[(p+2)%3]
    if (p + 2 < NT) {
      int s2 = cur + 2;
      if (s2 >= 3) s2 -= 3;
      stageKt(p + 2, s2);
    }
    // frag reads from buf[cur] (compiler interleaves lgkmcnt with MFMA)
    const int cof = cur * 8192;
#pragma unroll
    for (int mi = 0; mi < 4; ++mi)
      aF[mi] = *(const bf16x8*)(AsB + cof + aBase + mi * 1024);
#pragma unroll
    for (int nj = 0; nj < 4; ++nj)
      bF[nj] = *(const bf16x8*)(BsB + cof + bBase + nj * 1024);
    __builtin_amdgcn_s_setprio(1);
#pragma unroll
    for (int mi = 0; mi < 4; ++mi)
#pragma unroll
      for (int nj = 0; nj < 4; ++nj)
        acc[mi][nj] = __builtin_amdgcn_mfma_f32_16x16x32_bf16(
            aF[mi], bF[nj], acc[mi][nj], 0, 0, 0);
    __builtin_amdgcn_s_setprio(0);
    // gate: next phase reads buf[p+1] -> its stage must have landed
    if (p + 2 < NT) {
      asm volatile("s_waitcnt vmcnt(4)" ::: "memory");
    } else if (p + 1 < NT) {
      asm volatile("s_waitcnt vmcnt(0)" ::: "memory");
    }
    if (p + 1 < NT) {
      __builtin_amdgcn_sched_barrier(0);
      __builtin_amdgcn_s_barrier();
      __builtin_amdgcn_sched_barrier(0);
    }
    ++cur;
    if (cur >= 3) cur = 0;
  }

  // epilogue: C/D layout col=lane&15, row=(lane>>4)*4+j
#pragma unroll
  for (int mi = 0; mi < 4; ++mi) {
    const int row = m0 + wm * 64 + mi * 16 + (l >> 4) * 4;
#pragma unroll
    for (int nj = 0; nj < 4; ++nj) {
      const int col = n0 + wn * 64 + nj * 16 + l15;
#pragma unroll
      for (int j = 0; j < 4; ++j) {
        float v = acc[mi][nj][j];
        if (EP == 0) {
          ((float*)C)[(size_t)(row + j) * N + col] = v;
        } else {
          const int cls = col >> 10;
          if (cls == 1 || cls == 2) v = fast_sigmoid(v);
          else if (cls == 3) v = fast_tanh(v);
          ((bf16*)C)[(size_t)(row + j) * N + col] = __float2bfloat16(v);
        }
      }
    }
  }
}

// ---------------------------------------------------------------------------
// Fallback fp32-B GEMM (tier-3 out-proj only)
// ---------------------------------------------------------------------------
#define BM 64
#define BN 64
#define BKK 16
__global__ __launch_bounds__(256) void gemm_nt_kernel(
    const bf16* __restrict__ A, const float* __restrict__ B,
    float* __restrict__ C, int M, int N, int K) {
  __shared__ float Asm[BKK][BM + 1];
  __shared__ float Bsm[BKK][BN + 1];
  const int n0 = blockIdx.x * BN;
  const int m0 = blockIdx.y * BM;
  const int tid = threadIdx.x;
  const int tx = tid & 15, ty = tid >> 4;
  const int lk = tid & 15, lr = tid >> 4;
  float acc[4][4] = {};
  for (int k0 = 0; k0 < K; k0 += BKK) {
#pragma unroll
    for (int p = 0; p < 4; ++p) {
      Asm[lk][lr + 16 * p] =
          __bfloat162float(A[(size_t)(m0 + lr + 16 * p) * K + (k0 + lk)]);
      Bsm[lk][lr + 16 * p] = B[(size_t)(n0 + lr + 16 * p) * K + (k0 + lk)];
    }
    __syncthreads();
#pragma unroll
    for (int kk = 0; kk < BKK; ++kk) {
      float a[4], b[4];
#pragma unroll
      for (int i = 0; i < 4; ++i) a[i] = Asm[kk][ty * 4 + i];
#pragma unroll
      for (int j = 0; j < 4; ++j) b[j] = Bsm[kk][tx * 4 + j];
#pragma unroll
      for (int i = 0; i < 4; ++i)
#pragma unroll
        for (int j = 0; j < 4; ++j) acc[i][j] += a[i] * b[j];
    }
    __syncthreads();
  }
#pragma unroll
  for (int i = 0; i < 4; ++i)
#pragma unroll
    for (int j = 0; j < 4; ++j)
      C[(size_t)(m0 + ty * 4 + i) * N + (n0 + tx * 4 + j)] = acc[i][j];
}

// ---------------------------------------------------------------------------
// Chunked scan, 8 channels/thread (16B bf16 loads)
// ---------------------------------------------------------------------------
__global__ __launch_bounds__(256) void scan_chunk_kernel(
    const bf16* __restrict__ u, float* __restrict__ cA,
    float* __restrict__ cB, int nchunk, int tchunk) {
  int idx = blockIdx.x * 256 + threadIdx.x;
  int c8 = (idx & (DD / 8 - 1)) * 8;
  int chunk = (idx / (DD / 8)) % nchunk;
  int b = idx / ((DD / 8) * nchunk);
  const bf16* ub = u + (size_t)b * TT * 4 * DD;
  float Aacc[8], Bacc[8];
#pragma unroll
  for (int j = 0; j < 8; ++j) { Aacc[j] = 1.0f; Bacc[j] = 0.0f; }
  int t0 = chunk * tchunk;
  for (int t = t0; t < t0 + tchunk; ++t) {
    const bf16* row = ub + (size_t)t * 4 * DD;
    u16x8v dv = *(const u16x8v*)(row + 2 * DD + c8);
    u16x8v iv = *(const u16x8v*)(row + 3 * DD + c8);
#pragma unroll
    for (int j = 0; j < 8; ++j) {
      float dec = b2f(dv[j]), inj = b2f(iv[j]);
      Aacc[j] *= dec;
      Bacc[j] = dec * Bacc[j] + (1.0f - dec) * inj;
    }
  }
  int base = (b * nchunk + chunk) * DD + c8;
#pragma unroll
  for (int j = 0; j < 8; ++j) { cA[base + j] = Aacc[j]; cB[base + j] = Bacc[j]; }
}

__global__ __launch_bounds__(256) void scan_prefix_kernel(
    const float* __restrict__ cA, const float* __restrict__ cB,
    float* __restrict__ S, int nchunk) {
  int idx = blockIdx.x * 256 + threadIdx.x;
  int c = idx % DD;
  int b = idx / DD;
  float s = 0.0f;
  for (int j = 0; j < nchunk; ++j) {
    int e = (b * nchunk + j) * DD + c;
    S[e] = s;
    s = cA[e] * s + cB[e];
  }
}

__global__ __launch_bounds__(256) void scan_out_kernel(
    const bf16* __restrict__ u, const float* __restrict__ S,
    bf16* __restrict__ y, int nchunk, int tchunk) {
  int idx = blockIdx.x * 256 + threadIdx.x;
  int c8 = (idx & (DD / 8 - 1)) * 8;
  int chunk = (idx / (DD / 8)) % nchunk;
  int b = idx / ((DD / 8) * nchunk);
  const bf16* ub = u + (size_t)b * TT * 4 * DD;
  bf16* yb = y + (size_t)b * TT * DD;
  float st[8];
  int sbase = (b * nchunk + chunk) * DD + c8;
#pragma unroll
  for (int j = 0; j < 8; ++j) st[j] = S[sbase + j];
  int t0 = chunk * tchunk;
  for (int t = t0; t < t0 + tchunk; ++t) {
    const bf16* row = ub + (size_t)t * 4 * DD;
    u16x8v vv = *(const u16x8v*)(row + c8);
    u16x8v gv = *(const u16x8v*)(row + DD + c8);
    u16x8v dv = *(const u16x8v*)(row + 2 * DD + c8);
    u16x8v iv = *(const u16x8v*)(row + 3 * DD + c8);
    u16x8v ov;
#pragma unroll
    for (int j = 0; j < 8; ++j) {
      float dec = b2f(dv[j]), inj = b2f(iv[j]);
      float g = b2f(gv[j]), v = b2f(vv[j]);
      st[j] = dec * st[j] + (1.0f - dec) * inj;
      ov[j] = f2b(g * v + (1.0f - g) * st[j]);
    }
    *(u16x8v*)(yb + (size_t)t * DD + c8) = ov;
  }
}

// ---------------------------------------------------------------------------
extern "C" void kernel_launch(void* const* d_in, const int* in_sizes, int n_in,
                              void* d_out, int out_size, void* d_ws,
                              size_t ws_size, hipStream_t stream) {
  const float* x = (const float*)d_in[0];
  const float* Wc = (const float*)d_in[1];
  const float* Wp = (const float*)d_in[2];
  const float* Wo = (const float*)d_in[3];
  float* out = (float*)d_out;

  const size_t nb = (size_t)TT * DD;

  auto need = [&](int nbat, int nchunk, bool wob) -> size_t {
    return (size_t)nbat * nb * 2 + (size_t)nbat * 4 * nb * 2 +
           (size_t)4 * DD * DD * 2 + (wob ? (size_t)DD * DD * 2 : 0) +
           (size_t)3 * nbat * nchunk * DD * 4;
  };

  int nbat, nchunk;
  bool haveWob;
  if (ws_size >= need(4, 64, true)) {
    nbat = 4; nchunk = 64; haveWob = true;
  } else if (ws_size >= need(1, 64, true)) {
    nbat = 1; nchunk = 64; haveWob = true;
  } else {
    nbat = 1; nchunk = 16; haveWob = false;
  }
  const int tchunk = TT / nchunk;

  char* p = (char*)d_ws;
  bf16* Wpb = (bf16*)p;  p += (size_t)4 * DD * DD * 2;
  bf16* Wob = nullptr;
  if (haveWob) { Wob = (bf16*)p; p += (size_t)DD * DD * 2; }
  bf16* xm = (bf16*)p;   p += (size_t)nbat * nb * 2;  // also y
  bf16* u = (bf16*)p;    p += (size_t)nbat * 4 * nb * 2;
  float* cA = (float*)p; p += (size_t)nbat * nchunk * DD * 4;
  float* cB = (float*)p; p += (size_t)nbat * nchunk * DD * 4;
  float* S = (float*)p;
  bf16* y = xm;

  w2bf_kernel<<<(4 * DD * DD) / 256, 256, 0, stream>>>(Wp, Wpb, 4 * DD * DD);
  if (haveWob)
    w2bf_kernel<<<(DD * DD) / 256, 256, 0, stream>>>(Wo, Wob, DD * DD);

  for (int b0 = 0; b0 < BB; b0 += nbat) {
    const float* xb = x + (size_t)b0 * nb;
    float* outb = out + (size_t)b0 * nb;
    const int Mtot = nbat * TT;
    const int total4 = (int)(nbat * nb / 4);

    conv_add_kernel<<<total4 / 256, 256, 0, stream>>>(xb, Wc, xm, total4);

    {  // u = act(xm @ Wp^T): M=Mtot, N=4096, K=1024
      const int MB = Mtot / 128;
      const int nwg = MB * (4 * DD / 128);
      gemm128_kernel<1><<<nwg, 256, 0, stream>>>(xm, Wpb, u, Mtot, 4 * DD, DD,
                                                 MB);
    }
    {
      int nthreads = nbat * nchunk * (DD / 8);
      scan_chunk_kernel<<<nthreads / 256, 256, 0, stream>>>(u, cA, cB, nchunk,
                                                            tchunk);
      scan_prefix_kernel<<<(nbat * DD) / 256, 256, 0, stream>>>(cA, cB, S,
                                                                nchunk);
      scan_out_kernel<<<nthreads / 256, 256, 0, stream>>>(u, S, y, nchunk,
                                                          tchunk);
    }
    if (haveWob) {  // out = y @ Wo^T: M=Mtot, N=1024, K=1024
      const int MB = Mtot / 128;
      const int nwg = MB * (DD / 128);
      gemm128_kernel<0><<<nwg, 256, 0, stream>>>(y, Wob, outb, Mtot, DD, DD,
                                                 MB);
    } else {
      dim3 grid(DD / BN, Mtot / BM);
      gemm_nt_kernel<<<grid, 256, 0, stream>>>(y, Wo, outb, Mtot, DD, DD);
    }
  }
}

// Round 10
// 340.591 us; speedup vs baseline: 1.0888x; 1.0878x over previous
//
#include <hip/hip_runtime.h>
#include <hip/hip_bf16.h>
#include <math.h>

typedef __hip_bfloat16 bf16;
typedef __bf16 bf16x8 __attribute__((ext_vector_type(8)));
typedef float f32x4 __attribute__((ext_vector_type(4)));
typedef float f32x4v __attribute__((ext_vector_type(4)));
typedef unsigned short u16x8v __attribute__((ext_vector_type(8)));
typedef unsigned short u16x4v __attribute__((ext_vector_type(4)));

#define AS1 __attribute__((address_space(1)))
#define AS3 __attribute__((address_space(3)))

// Problem constants
#define BB 4
#define TT 4096
#define DD 1024

__device__ __forceinline__ float fast_sigmoid(float x) {
  return 1.0f / (1.0f + __expf(-x));
}
__device__ __forceinline__ float fast_tanh(float x) {
  return 2.0f / (1.0f + __expf(-2.0f * x)) - 1.0f;
}
__device__ __forceinline__ float b2f(unsigned short u) {
  union { unsigned int i; float f; } x;
  x.i = ((unsigned int)u) << 16;
  return x.f;
}
__device__ __forceinline__ unsigned short f2b(float f) {
  union { bf16 h; unsigned short u; } x;
  x.h = __float2bfloat16(f);
  return x.u;
}

// ---------------------------------------------------------------------------
// Weight fp32 -> bf16
// ---------------------------------------------------------------------------
__global__ __launch_bounds__(256) void w2bf_kernel(const float* __restrict__ w,
                                                   bf16* __restrict__ o,
                                                   int n) {
  int i = blockIdx.x * 256 + threadIdx.x;
  if (i < n) o[i] = __float2bfloat16(w[i]);
}

// ---------------------------------------------------------------------------
// conv + add -> bf16, 4 channels / thread
// ---------------------------------------------------------------------------
__global__ __launch_bounds__(256) void conv_add_kernel(
    const float* __restrict__ x, const float* __restrict__ Wc,
    bf16* __restrict__ xm, int total4) {
  int i = blockIdx.x * 256 + threadIdx.x;
  if (i >= total4) return;
  int c4 = (i & (DD / 4 - 1)) * 4;
  int t = (i / (DD / 4)) % TT;
  size_t base = (size_t)i * 4;
  f32x4v x0 = *(const f32x4v*)(x + base);
  f32x4v p1 = (t >= 1) ? *(const f32x4v*)(x + base - DD) : (f32x4v)0.0f;
  f32x4v p2 = (t >= 2) ? *(const f32x4v*)(x + base - 2 * DD) : (f32x4v)0.0f;
  f32x4v p3 = (t >= 3) ? *(const f32x4v*)(x + base - 3 * DD) : (f32x4v)0.0f;
  u16x4v o;
#pragma unroll
  for (int j = 0; j < 4; ++j) {
    f32x4v w = *(const f32x4v*)(Wc + (size_t)(c4 + j) * 4);
    float acc = x0[j] + w[3] * x0[j] + w[2] * p1[j] + w[1] * p2[j] +
                w[0] * p3[j];
    o[j] = f2b(acc);
  }
  *(u16x4v*)(xm + base) = o;
}

// ---------------------------------------------------------------------------
// 128x128 MFMA GEMM, BK=32, 4 waves (2Mx2N), double-buffered 32 KiB LDS,
// ~4 WG/CU (cross-WG overlap hides sync stalls, m114). r7 structure with
// CORRECTED swizzle: conflict-groups are quarter-waves (16 lanes, fixed
// lh=l>>4); old XOR(row&3) left 4 lanes/stripe-position (4-way, 1.68e7
// conflicts); new XOR((row>>1)&3) gives exactly 2 lanes/position (free):
//   stage: lane l -> row l>>2, phys slot l&3; source logical slot
//          (l&3)^((l>>3)&3)     [row>>1 = l>>3 within a 16-row chunk]
//   read:  row = mi*16+l15, logical slot lh=l>>4; phys = lh^((l15>>1)&3)
// Per phase: 8 ds_read_b128 -> barrier -> 16 MFMA -> stage kt+2 -> vmcnt(4)
// gate -> barrier. C[m][n] = sum_k A[m][k]*B[n][k]; bf16; K%64==0,
// M,N%128==0, MB%8==0.
// EP=0: fp32 C. EP=1: bf16 C with per-1024-col activation.
// ---------------------------------------------------------------------------
template <int EP>
__global__ __launch_bounds__(256, 4) void gemm128_kernel(
    const bf16* __restrict__ A, const bf16* __restrict__ B,
    void* __restrict__ C, int M, int N, int K, int MB) {
  __shared__ __align__(16) bf16 As[2][128][32];
  __shared__ __align__(16) bf16 Bs[2][128][32];

  const int tid = threadIdx.x;
  const int wv = tid >> 6, l = tid & 63;
  const int wm = wv >> 1, wn = wv & 1;

  // XCD-chunked bijective block mapping
  const int bid = blockIdx.x;
  const int xcd = bid & 7, ii = bid >> 3;
  const int mb8 = MB >> 3;
  const int bm = xcd * mb8 + (ii % mb8);
  const int bn = ii / mb8;
  const int m0 = bm * 128, n0 = bn * 128;

  // staging: lane l -> row base + (l>>2), phys 16B slot (l&3);
  // source logical slot = (l&3) ^ ((l>>3)&3)   [conflict-free swizzle]
  const int srow = l >> 2;
  const int scolE = ((l & 3) ^ ((l >> 3) & 3)) * 8;
  const bf16* Ab = A + (size_t)(m0 + wv * 32 + srow) * K + scolE;
  const bf16* Bb = B + (size_t)(n0 + wv * 32 + srow) * K + scolE;

  // frag reads: row r = mi*16 + l15, logical slot = l>>4,
  // phys byte = ((l>>4) ^ ((l15>>1)&3)) * 16
  const int l15 = l & 15;
  const int physColB = ((l >> 4) ^ ((l >> 1) & 3)) * 16;
  const char* AsB = (const char*)As;
  const char* BsB = (const char*)Bs;
  const int aBase = wm * 4096 + l15 * 64 + physColB;
  const int bBase = wn * 4096 + l15 * 64 + physColB;

  auto stageKt = [&](int kt, int slot) {
    const int k0 = kt * 32;
#pragma unroll
    for (int j = 0; j < 2; ++j) {
      __builtin_amdgcn_global_load_lds(
          (const AS1 void*)(Ab + (size_t)(j * 16) * K + k0),
          (AS3 void*)&As[slot][wv * 32 + j * 16][0], 16, 0, 0);
      __builtin_amdgcn_global_load_lds(
          (const AS1 void*)(Bb + (size_t)(j * 16) * K + k0),
          (AS3 void*)&Bs[slot][wv * 32 + j * 16][0], 16, 0, 0);
    }
  };

  f32x4 acc[4][4];
#pragma unroll
  for (int i = 0; i < 4; ++i)
#pragma unroll
    for (int j = 0; j < 4; ++j) acc[i][j] = (f32x4)0.0f;

  const int NT = K >> 5;

  stageKt(0, 0);
  stageKt(1, 1);
  asm volatile("s_waitcnt vmcnt(4)" ::: "memory");  // kt0 landed
  __builtin_amdgcn_s_barrier();

  bf16x8 aF[4], bF[4];

#pragma unroll 1
  for (int t = 0; t < NT / 2; ++t) {
#pragma unroll
    for (int s = 0; s < 2; ++s) {
      const int kt = 2 * t + s;
      const int sof = s * 8192;
#pragma unroll
      for (int mi = 0; mi < 4; ++mi)
        aF[mi] = *(const bf16x8*)(AsB + aBase + sof + mi * 1024);
#pragma unroll
      for (int nj = 0; nj < 4; ++nj)
        bF[nj] = *(const bf16x8*)(BsB + bBase + sof + nj * 1024);
      __builtin_amdgcn_sched_barrier(0);
      __builtin_amdgcn_s_barrier();
      __builtin_amdgcn_s_setprio(1);
#pragma unroll
      for (int mi = 0; mi < 4; ++mi)
#pragma unroll
        for (int nj = 0; nj < 4; ++nj)
          acc[mi][nj] = __builtin_amdgcn_mfma_f32_16x16x32_bf16(
              aF[mi], bF[nj], acc[mi][nj], 0, 0, 0);
      __builtin_amdgcn_s_setprio(0);
      if (kt + 2 < NT) stageKt(kt + 2, s);
      if (kt + 1 < NT) {
        if (kt + 2 < NT)
          asm volatile("s_waitcnt vmcnt(4)" ::: "memory");
        else
          asm volatile("s_waitcnt vmcnt(0)" ::: "memory");
      }
      __builtin_amdgcn_sched_barrier(0);
      __builtin_amdgcn_s_barrier();
    }
  }

  // epilogue: C/D layout col=lane&15, row=(lane>>4)*4+j
#pragma unroll
  for (int mi = 0; mi < 4; ++mi) {
    const int row = m0 + wm * 64 + mi * 16 + (l >> 4) * 4;
#pragma unroll
    for (int nj = 0; nj < 4; ++nj) {
      const int col = n0 + wn * 64 + nj * 16 + l15;
#pragma unroll
      for (int j = 0; j < 4; ++j) {
        float v = acc[mi][nj][j];
        if (EP == 0) {
          ((float*)C)[(size_t)(row + j) * N + col] = v;
        } else {
          const int cls = col >> 10;
          if (cls == 1 || cls == 2) v = fast_sigmoid(v);
          else if (cls == 3) v = fast_tanh(v);
          ((bf16*)C)[(size_t)(row + j) * N + col] = __float2bfloat16(v);
        }
      }
    }
  }
}

// ---------------------------------------------------------------------------
// Fallback fp32-B GEMM (tier-3 out-proj only)
// ---------------------------------------------------------------------------
#define BM 64
#define BN 64
#define BKK 16
__global__ __launch_bounds__(256) void gemm_nt_kernel(
    const bf16* __restrict__ A, const float* __restrict__ B,
    float* __restrict__ C, int M, int N, int K) {
  __shared__ float Asm[BKK][BM + 1];
  __shared__ float Bsm[BKK][BN + 1];
  const int n0 = blockIdx.x * BN;
  const int m0 = blockIdx.y * BM;
  const int tid = threadIdx.x;
  const int tx = tid & 15, ty = tid >> 4;
  const int lk = tid & 15, lr = tid >> 4;
  float acc[4][4] = {};
  for (int k0 = 0; k0 < K; k0 += BKK) {
#pragma unroll
    for (int p = 0; p < 4; ++p) {
      Asm[lk][lr + 16 * p] =
          __bfloat162float(A[(size_t)(m0 + lr + 16 * p) * K + (k0 + lk)]);
      Bsm[lk][lr + 16 * p] = B[(size_t)(n0 + lr + 16 * p) * K + (k0 + lk)];
    }
    __syncthreads();
#pragma unroll
    for (int kk = 0; kk < BKK; ++kk) {
      float a[4], b[4];
#pragma unroll
      for (int i = 0; i < 4; ++i) a[i] = Asm[kk][ty * 4 + i];
#pragma unroll
      for (int j = 0; j < 4; ++j) b[j] = Bsm[kk][tx * 4 + j];
#pragma unroll
      for (int i = 0; i < 4; ++i)
#pragma unroll
        for (int j = 0; j < 4; ++j) acc[i][j] += a[i] * b[j];
    }
    __syncthreads();
  }
#pragma unroll
  for (int i = 0; i < 4; ++i)
#pragma unroll
    for (int j = 0; j < 4; ++j)
      C[(size_t)(m0 + ty * 4 + i) * N + (n0 + tx * 4 + j)] = acc[i][j];
}

// ---------------------------------------------------------------------------
// Chunked scan, 8 channels/thread (16B bf16 loads)
// ---------------------------------------------------------------------------
__global__ __launch_bounds__(256) void scan_chunk_kernel(
    const bf16* __restrict__ u, float* __restrict__ cA,
    float* __restrict__ cB, int nchunk, int tchunk) {
  int idx = blockIdx.x * 256 + threadIdx.x;
  int c8 = (idx & (DD / 8 - 1)) * 8;
  int chunk = (idx / (DD / 8)) % nchunk;
  int b = idx / ((DD / 8) * nchunk);
  const bf16* ub = u + (size_t)b * TT * 4 * DD;
  float Aacc[8], Bacc[8];
#pragma unroll
  for (int j = 0; j < 8; ++j) { Aacc[j] = 1.0f; Bacc[j] = 0.0f; }
  int t0 = chunk * tchunk;
  for (int t = t0; t < t0 + tchunk; ++t) {
    const bf16* row = ub + (size_t)t * 4 * DD;
    u16x8v dv = *(const u16x8v*)(row + 2 * DD + c8);
    u16x8v iv = *(const u16x8v*)(row + 3 * DD + c8);
#pragma unroll
    for (int j = 0; j < 8; ++j) {
      float dec = b2f(dv[j]), inj = b2f(iv[j]);
      Aacc[j] *= dec;
      Bacc[j] = dec * Bacc[j] + (1.0f - dec) * inj;
    }
  }
  int base = (b * nchunk + chunk) * DD + c8;
#pragma unroll
  for (int j = 0; j < 8; ++j) { cA[base + j] = Aacc[j]; cB[base + j] = Bacc[j]; }
}

__global__ __launch_bounds__(256) void scan_prefix_kernel(
    const float* __restrict__ cA, const float* __restrict__ cB,
    float* __restrict__ S, int nchunk) {
  int idx = blockIdx.x * 256 + threadIdx.x;
  int c = idx % DD;
  int b = idx / DD;
  float s = 0.0f;
  for (int j = 0; j < nchunk; ++j) {
    int e = (b * nchunk + j) * DD + c;
    S[e] = s;
    s = cA[e] * s + cB[e];
  }
}

__global__ __launch_bounds__(256) void scan_out_kernel(
    const bf16* __restrict__ u, const float* __restrict__ S,
    bf16* __restrict__ y, int nchunk, int tchunk) {
  int idx = blockIdx.x * 256 + threadIdx.x;
  int c8 = (idx & (DD / 8 - 1)) * 8;
  int chunk = (idx / (DD / 8)) % nchunk;
  int b = idx / ((DD / 8) * nchunk);
  const bf16* ub = u + (size_t)b * TT * 4 * DD;
  bf16* yb = y + (size_t)b * TT * DD;
  float st[8];
  int sbase = (b * nchunk + chunk) * DD + c8;
#pragma unroll
  for (int j = 0; j < 8; ++j) st[j] = S[sbase + j];
  int t0 = chunk * tchunk;
  for (int t = t0; t < t0 + tchunk; ++t) {
    const bf16* row = ub + (size_t)t * 4 * DD;
    u16x8v vv = *(const u16x8v*)(row + c8);
    u16x8v gv = *(const u16x8v*)(row + DD + c8);
    u16x8v dv = *(const u16x8v*)(row + 2 * DD + c8);
    u16x8v iv = *(const u16x8v*)(row + 3 * DD + c8);
    u16x8v ov;
#pragma unroll
    for (int j = 0; j < 8; ++j) {
      float dec = b2f(dv[j]), inj = b2f(iv[j]);
      float g = b2f(gv[j]), v = b2f(vv[j]);
      st[j] = dec * st[j] + (1.0f - dec) * inj;
      ov[j] = f2b(g * v + (1.0f - g) * st[j]);
    }
    *(u16x8v*)(yb + (size_t)t * DD + c8) = ov;
  }
}

// ---------------------------------------------------------------------------
extern "C" void kernel_launch(void* const* d_in, const int* in_sizes, int n_in,
                              void* d_out, int out_size, void* d_ws,
                              size_t ws_size, hipStream_t stream) {
  const float* x = (const float*)d_in[0];
  const float* Wc = (const float*)d_in[1];
  const float* Wp = (const float*)d_in[2];
  const float* Wo = (const float*)d_in[3];
  float* out = (float*)d_out;

  const size_t nb = (size_t)TT * DD;

  auto need = [&](int nbat, int nchunk, bool wob) -> size_t {
    return (size_t)nbat * nb * 2 + (size_t)nbat * 4 * nb * 2 +
           (size_t)4 * DD * DD * 2 + (wob ? (size_t)DD * DD * 2 : 0) +
           (size_t)3 * nbat * nchunk * DD * 4;
  };

  int nbat, nchunk;
  bool haveWob;
  if (ws_size >= need(4, 64, true)) {
    nbat = 4; nchunk = 64; haveWob = true;
  } else if (ws_size >= need(1, 64, true)) {
    nbat = 1; nchunk = 64; haveWob = true;
  } else {
    nbat = 1; nchunk = 16; haveWob = false;
  }
  const int tchunk = TT / nchunk;

  char* p = (char*)d_ws;
  bf16* Wpb = (bf16*)p;  p += (size_t)4 * DD * DD * 2;
  bf16* Wob = nullptr;
  if (haveWob) { Wob = (bf16*)p; p += (size_t)DD * DD * 2; }
  bf16* xm = (bf16*)p;   p += (size_t)nbat * nb * 2;  // also y
  bf16* u = (bf16*)p;    p += (size_t)nbat * 4 * nb * 2;
  float* cA = (float*)p; p += (size_t)nbat * nchunk * DD * 4;
  float* cB = (float*)p; p += (size_t)nbat * nchunk * DD * 4;
  float* S = (float*)p;
  bf16* y = xm;

  w2bf_kernel<<<(4 * DD * DD) / 256, 256, 0, stream>>>(Wp, Wpb, 4 * DD * DD);
  if (haveWob)
    w2bf_kernel<<<(DD * DD) / 256, 256, 0, stream>>>(Wo, Wob, DD * DD);

  for (int b0 = 0; b0 < BB; b0 += nbat) {
    const float* xb = x + (size_t)b0 * nb;
    float* outb = out + (size_t)b0 * nb;
    const int Mtot = nbat * TT;
    const int total4 = (int)(nbat * nb / 4);

    conv_add_kernel<<<total4 / 256, 256, 0, stream>>>(xb, Wc, xm, total4);

    {  // u = act(xm @ Wp^T): M=Mtot, N=4096, K=1024
      const int MB = Mtot / 128;
      const int nwg = MB * (4 * DD / 128);
      gemm128_kernel<1><<<nwg, 256, 0, stream>>>(xm, Wpb, u, Mtot, 4 * DD, DD,
                                                 MB);
    }
    {
      int nthreads = nbat * nchunk * (DD / 8);
      scan_chunk_kernel<<<nthreads / 256, 256, 0, stream>>>(u, cA, cB, nchunk,
                                                            tchunk);
      scan_prefix_kernel<<<(nbat * DD) / 256, 256, 0, stream>>>(cA, cB, S,
                                                                nchunk);
      scan_out_kernel<<<nthreads / 256, 256, 0, stream>>>(u, S, y, nchunk,
                                                          tchunk);
    }
    if (haveWob) {  // out = y @ Wo^T: M=Mtot, N=1024, K=1024
      const int MB = Mtot / 128;
      const int nwg = MB * (DD / 128);
      gemm128_kernel<0><<<nwg, 256, 0, stream>>>(y, Wob, outb, Mtot, DD, DD,
                                                 MB);
    } else {
      dim3 grid(DD / BN, Mtot / BM);
      gemm_nt_kernel<<<grid, 256, 0, stream>>>(y, Wo, outb, Mtot, DD, DD);
    }
  }
}

// Round 11
// 330.108 us; speedup vs baseline: 1.1234x; 1.0318x over previous
//
#include <hip/hip_runtime.h>
#include <hip/hip_bf16.h>
#include <math.h>

typedef __hip_bfloat16 bf16;
typedef __bf16 bf16x8 __attribute__((ext_vector_type(8)));
typedef float f32x4 __attribute__((ext_vector_type(4)));
typedef float f32x4v __attribute__((ext_vector_type(4)));
typedef unsigned short u16x8v __attribute__((ext_vector_type(8)));
typedef unsigned short u16x4v __attribute__((ext_vector_type(4)));

#define AS1 __attribute__((address_space(1)))
#define AS3 __attribute__((address_space(3)))

// Problem constants
#define BB 4
#define TT 4096
#define DD 1024

__device__ __forceinline__ float fast_sigmoid(float x) {
  return 1.0f / (1.0f + __expf(-x));
}
__device__ __forceinline__ float fast_tanh(float x) {
  return 2.0f / (1.0f + __expf(-2.0f * x)) - 1.0f;
}
__device__ __forceinline__ float b2f(unsigned short u) {
  union { unsigned int i; float f; } x;
  x.i = ((unsigned int)u) << 16;
  return x.f;
}
__device__ __forceinline__ unsigned short f2b(float f) {
  union { bf16 h; unsigned short u; } x;
  x.h = __float2bfloat16(f);
  return x.u;
}

// ---------------------------------------------------------------------------
// Weight fp32 -> bf16
// ---------------------------------------------------------------------------
__global__ __launch_bounds__(256) void w2bf_kernel(const float* __restrict__ w,
                                                   bf16* __restrict__ o,
                                                   int n) {
  int i = blockIdx.x * 256 + threadIdx.x;
  if (i < n) o[i] = __float2bfloat16(w[i]);
}

// ---------------------------------------------------------------------------
// conv + add -> bf16, 4 channels / thread
// ---------------------------------------------------------------------------
__global__ __launch_bounds__(256) void conv_add_kernel(
    const float* __restrict__ x, const float* __restrict__ Wc,
    bf16* __restrict__ xm, int total4) {
  int i = blockIdx.x * 256 + threadIdx.x;
  if (i >= total4) return;
  int c4 = (i & (DD / 4 - 1)) * 4;
  int t = (i / (DD / 4)) % TT;
  size_t base = (size_t)i * 4;
  f32x4v x0 = *(const f32x4v*)(x + base);
  f32x4v p1 = (t >= 1) ? *(const f32x4v*)(x + base - DD) : (f32x4v)0.0f;
  f32x4v p2 = (t >= 2) ? *(const f32x4v*)(x + base - 2 * DD) : (f32x4v)0.0f;
  f32x4v p3 = (t >= 3) ? *(const f32x4v*)(x + base - 3 * DD) : (f32x4v)0.0f;
  u16x4v o;
#pragma unroll
  for (int j = 0; j < 4; ++j) {
    f32x4v w = *(const f32x4v*)(Wc + (size_t)(c4 + j) * 4);
    float acc = x0[j] + w[3] * x0[j] + w[2] * p1[j] + w[1] * p2[j] +
                w[0] * p3[j];
    o[j] = f2b(acc);
  }
  *(u16x4v*)(xm + base) = o;
}

// ---------------------------------------------------------------------------
// 256x128 MFMA GEMM, BK=32, 4 waves stacked on M (each wave owns 64x128),
// double-buffered 48 KiB LDS. Raises LDS arithmetic intensity 32->44
// FLOP/byte (r10's 64x64/wave was LDS-BW-capped at ~60% MfmaUtil ceiling:
// 32 KiB LDS-read vs 64 MFMA per WG-phase). Per phase: 12 ds_read_b128 ->
// barrier -> 32 MFMA -> stage kt+2 (6 gll) -> vmcnt(6) gate -> barrier.
// Swizzle identical to r10 (measured 0 conflicts; bank model: 2 lanes/bank):
//   stage: lane l -> row l>>2, phys slot l&3; source logical slot
//          (l&3)^((l>>3)&3)
//   read:  row base+l15, phys slot = (l>>4) ^ ((l>>1)&3)
// C[m][n] = sum_k A[m][k]*B[n][k]; bf16; K%64==0, M%256==0, N%128==0,
// MB%8==0. EP=0: fp32 C. EP=1: bf16 C with per-1024-col activation.
// ---------------------------------------------------------------------------
template <int EP>
__global__ __launch_bounds__(256, 2) void gemm256x128_kernel(
    const bf16* __restrict__ A, const bf16* __restrict__ B,
    void* __restrict__ C, int M, int N, int K, int MB) {
  __shared__ __align__(16) bf16 As[2][256][32];
  __shared__ __align__(16) bf16 Bs[2][128][32];

  const int tid = threadIdx.x;
  const int wv = tid >> 6, l = tid & 63;

  // XCD-chunked bijective block mapping
  const int bid = blockIdx.x;
  const int xcd = bid & 7, ii = bid >> 3;
  const int mb8 = MB >> 3;
  const int bm = xcd * mb8 + (ii % mb8);
  const int bn = ii / mb8;
  const int m0 = bm * 256, n0 = bn * 128;

  // staging source (pre-swizzled, r10-verified)
  const int srow = l >> 2;
  const int scolE = ((l & 3) ^ ((l >> 3) & 3)) * 8;
  const bf16* Ab = A + (size_t)(m0 + wv * 64 + srow) * K + scolE;
  const bf16* Bb = B + (size_t)(n0 + wv * 32 + srow) * K + scolE;

  // frag-read constants
  const int l15 = l & 15;
  const int physColB = ((l >> 4) ^ ((l >> 1) & 3)) * 16;
  const char* AsB = (const char*)As;
  const char* BsB = (const char*)Bs;
  const int aBase = wv * 4096 + l15 * 64 + physColB;  // wave's 64-row panel
  const int bBase = l15 * 64 + physColB;

  // stage K-tile kt into buffer slot: 4 A-chunks + 2 B-chunks per wave
  auto stageKt = [&](int kt, int slot) {
    const int k0 = kt * 32;
#pragma unroll
    for (int j = 0; j < 4; ++j)
      __builtin_amdgcn_global_load_lds(
          (const AS1 void*)(Ab + (size_t)(j * 16) * K + k0),
          (AS3 void*)&As[slot][wv * 64 + j * 16][0], 16, 0, 0);
#pragma unroll
    for (int j = 0; j < 2; ++j)
      __builtin_amdgcn_global_load_lds(
          (const AS1 void*)(Bb + (size_t)(j * 16) * K + k0),
          (AS3 void*)&Bs[slot][wv * 32 + j * 16][0], 16, 0, 0);
  };

  f32x4 acc[4][8];
#pragma unroll
  for (int i = 0; i < 4; ++i)
#pragma unroll
    for (int j = 0; j < 8; ++j) acc[i][j] = (f32x4)0.0f;

  const int NT = K >> 5;

  stageKt(0, 0);
  stageKt(1, 1);
  asm volatile("s_waitcnt vmcnt(6)" ::: "memory");  // kt0 landed
  __builtin_amdgcn_s_barrier();

  bf16x8 aF[4], bF[8];

#pragma unroll 1
  for (int t = 0; t < NT / 2; ++t) {
#pragma unroll
    for (int s = 0; s < 2; ++s) {
      const int kt = 2 * t + s;
      const int sofA = s * 16384;
      const int sofB = s * 8192;
#pragma unroll
      for (int mi = 0; mi < 4; ++mi)
        aF[mi] = *(const bf16x8*)(AsB + sofA + aBase + mi * 1024);
#pragma unroll
      for (int nj = 0; nj < 8; ++nj)
        bF[nj] = *(const bf16x8*)(BsB + sofB + bBase + nj * 1024);
      __builtin_amdgcn_sched_barrier(0);
      __builtin_amdgcn_s_barrier();
      __builtin_amdgcn_s_setprio(1);
#pragma unroll
      for (int mi = 0; mi < 4; ++mi)
#pragma unroll
        for (int nj = 0; nj < 8; ++nj)
          acc[mi][nj] = __builtin_amdgcn_mfma_f32_16x16x32_bf16(
              aF[mi], bF[nj], acc[mi][nj], 0, 0, 0);
      __builtin_amdgcn_s_setprio(0);
      if (kt + 2 < NT) stageKt(kt + 2, s);
      if (kt + 1 < NT) {
        if (kt + 2 < NT)
          asm volatile("s_waitcnt vmcnt(6)" ::: "memory");
        else
          asm volatile("s_waitcnt vmcnt(0)" ::: "memory");
      }
      __builtin_amdgcn_sched_barrier(0);
      __builtin_amdgcn_s_barrier();
    }
  }

  // epilogue: C/D layout col=lane&15, row=(lane>>4)*4+j
#pragma unroll
  for (int mi = 0; mi < 4; ++mi) {
    const int row = m0 + wv * 64 + mi * 16 + (l >> 4) * 4;
#pragma unroll
    for (int nj = 0; nj < 8; ++nj) {
      const int col = n0 + nj * 16 + l15;
#pragma unroll
      for (int j = 0; j < 4; ++j) {
        float v = acc[mi][nj][j];
        if (EP == 0) {
          ((float*)C)[(size_t)(row + j) * N + col] = v;
        } else {
          const int cls = col >> 10;
          if (cls == 1 || cls == 2) v = fast_sigmoid(v);
          else if (cls == 3) v = fast_tanh(v);
          ((bf16*)C)[(size_t)(row + j) * N + col] = __float2bfloat16(v);
        }
      }
    }
  }
}

// ---------------------------------------------------------------------------
// Fallback fp32-B GEMM (tier-3 out-proj only)
// ---------------------------------------------------------------------------
#define BM 64
#define BN 64
#define BKK 16
__global__ __launch_bounds__(256) void gemm_nt_kernel(
    const bf16* __restrict__ A, const float* __restrict__ B,
    float* __restrict__ C, int M, int N, int K) {
  __shared__ float Asm[BKK][BM + 1];
  __shared__ float Bsm[BKK][BN + 1];
  const int n0 = blockIdx.x * BN;
  const int m0 = blockIdx.y * BM;
  const int tid = threadIdx.x;
  const int tx = tid & 15, ty = tid >> 4;
  const int lk = tid & 15, lr = tid >> 4;
  float acc[4][4] = {};
  for (int k0 = 0; k0 < K; k0 += BKK) {
#pragma unroll
    for (int p = 0; p < 4; ++p) {
      Asm[lk][lr + 16 * p] =
          __bfloat162float(A[(size_t)(m0 + lr + 16 * p) * K + (k0 + lk)]);
      Bsm[lk][lr + 16 * p] = B[(size_t)(n0 + lr + 16 * p) * K + (k0 + lk)];
    }
    __syncthreads();
#pragma unroll
    for (int kk = 0; kk < BKK; ++kk) {
      float a[4], b[4];
#pragma unroll
      for (int i = 0; i < 4; ++i) a[i] = Asm[kk][ty * 4 + i];
#pragma unroll
      for (int j = 0; j < 4; ++j) b[j] = Bsm[kk][tx * 4 + j];
#pragma unroll
      for (int i = 0; i < 4; ++i)
#pragma unroll
        for (int j = 0; j < 4; ++j) acc[i][j] += a[i] * b[j];
    }
    __syncthreads();
  }
#pragma unroll
  for (int i = 0; i < 4; ++i)
#pragma unroll
    for (int j = 0; j < 4; ++j)
      C[(size_t)(m0 + ty * 4 + i) * N + (n0 + tx * 4 + j)] = acc[i][j];
}

// ---------------------------------------------------------------------------
// Chunked scan, 8 channels/thread (16B bf16 loads)
// ---------------------------------------------------------------------------
__global__ __launch_bounds__(256) void scan_chunk_kernel(
    const bf16* __restrict__ u, float* __restrict__ cA,
    float* __restrict__ cB, int nchunk, int tchunk) {
  int idx = blockIdx.x * 256 + threadIdx.x;
  int c8 = (idx & (DD / 8 - 1)) * 8;
  int chunk = (idx / (DD / 8)) % nchunk;
  int b = idx / ((DD / 8) * nchunk);
  const bf16* ub = u + (size_t)b * TT * 4 * DD;
  float Aacc[8], Bacc[8];
#pragma unroll
  for (int j = 0; j < 8; ++j) { Aacc[j] = 1.0f; Bacc[j] = 0.0f; }
  int t0 = chunk * tchunk;
  for (int t = t0; t < t0 + tchunk; ++t) {
    const bf16* row = ub + (size_t)t * 4 * DD;
    u16x8v dv = *(const u16x8v*)(row + 2 * DD + c8);
    u16x8v iv = *(const u16x8v*)(row + 3 * DD + c8);
#pragma unroll
    for (int j = 0; j < 8; ++j) {
      float dec = b2f(dv[j]), inj = b2f(iv[j]);
      Aacc[j] *= dec;
      Bacc[j] = dec * Bacc[j] + (1.0f - dec) * inj;
    }
  }
  int base = (b * nchunk + chunk) * DD + c8;
#pragma unroll
  for (int j = 0; j < 8; ++j) { cA[base + j] = Aacc[j]; cB[base + j] = Bacc[j]; }
}

__global__ __launch_bounds__(256) void scan_prefix_kernel(
    const float* __restrict__ cA, const float* __restrict__ cB,
    float* __restrict__ S, int nchunk) {
  int idx = blockIdx.x * 256 + threadIdx.x;
  int c = idx % DD;
  int b = idx / DD;
  float s = 0.0f;
  for (int j = 0; j < nchunk; ++j) {
    int e = (b * nchunk + j) * DD + c;
    S[e] = s;
    s = cA[e] * s + cB[e];
  }
}

__global__ __launch_bounds__(256) void scan_out_kernel(
    const bf16* __restrict__ u, const float* __restrict__ S,
    bf16* __restrict__ y, int nchunk, int tchunk) {
  int idx = blockIdx.x * 256 + threadIdx.x;
  int c8 = (idx & (DD / 8 - 1)) * 8;
  int chunk = (idx / (DD / 8)) % nchunk;
  int b = idx / ((DD / 8) * nchunk);
  const bf16* ub = u + (size_t)b * TT * 4 * DD;
  bf16* yb = y + (size_t)b * TT * DD;
  float st[8];
  int sbase = (b * nchunk + chunk) * DD + c8;
#pragma unroll
  for (int j = 0; j < 8; ++j) st[j] = S[sbase + j];
  int t0 = chunk * tchunk;
  for (int t = t0; t < t0 + tchunk; ++t) {
    const bf16* row = ub + (size_t)t * 4 * DD;
    u16x8v vv = *(const u16x8v*)(row + c8);
    u16x8v gv = *(const u16x8v*)(row + DD + c8);
    u16x8v dv = *(const u16x8v*)(row + 2 * DD + c8);
    u16x8v iv = *(const u16x8v*)(row + 3 * DD + c8);
    u16x8v ov;
#pragma unroll
    for (int j = 0; j < 8; ++j) {
      float dec = b2f(dv[j]), inj = b2f(iv[j]);
      float g = b2f(gv[j]), v = b2f(vv[j]);
      st[j] = dec * st[j] + (1.0f - dec) * inj;
      ov[j] = f2b(g * v + (1.0f - g) * st[j]);
    }
    *(u16x8v*)(yb + (size_t)t * DD + c8) = ov;
  }
}

// ---------------------------------------------------------------------------
extern "C" void kernel_launch(void* const* d_in, const int* in_sizes, int n_in,
                              void* d_out, int out_size, void* d_ws,
                              size_t ws_size, hipStream_t stream) {
  const float* x = (const float*)d_in[0];
  const float* Wc = (const float*)d_in[1];
  const float* Wp = (const float*)d_in[2];
  const float* Wo = (const float*)d_in[3];
  float* out = (float*)d_out;

  const size_t nb = (size_t)TT * DD;

  auto need = [&](int nbat, int nchunk, bool wob) -> size_t {
    return (size_t)nbat * nb * 2 + (size_t)nbat * 4 * nb * 2 +
           (size_t)4 * DD * DD * 2 + (wob ? (size_t)DD * DD * 2 : 0) +
           (size_t)3 * nbat * nchunk * DD * 4;
  };

  int nbat, nchunk;
  bool haveWob;
  if (ws_size >= need(4, 64, true)) {
    nbat = 4; nchunk = 64; haveWob = true;
  } else if (ws_size >= need(1, 64, true)) {
    nbat = 1; nchunk = 64; haveWob = true;
  } else {
    nbat = 1; nchunk = 16; haveWob = false;
  }
  const int tchunk = TT / nchunk;

  char* p = (char*)d_ws;
  bf16* Wpb = (bf16*)p;  p += (size_t)4 * DD * DD * 2;
  bf16* Wob = nullptr;
  if (haveWob) { Wob = (bf16*)p; p += (size_t)DD * DD * 2; }
  bf16* xm = (bf16*)p;   p += (size_t)nbat * nb * 2;  // also y
  bf16* u = (bf16*)p;    p += (size_t)nbat * 4 * nb * 2;
  float* cA = (float*)p; p += (size_t)nbat * nchunk * DD * 4;
  float* cB = (float*)p; p += (size_t)nbat * nchunk * DD * 4;
  float* S = (float*)p;
  bf16* y = xm;

  w2bf_kernel<<<(4 * DD * DD) / 256, 256, 0, stream>>>(Wp, Wpb, 4 * DD * DD);
  if (haveWob)
    w2bf_kernel<<<(DD * DD) / 256, 256, 0, stream>>>(Wo, Wob, DD * DD);

  for (int b0 = 0; b0 < BB; b0 += nbat) {
    const float* xb = x + (size_t)b0 * nb;
    float* outb = out + (size_t)b0 * nb;
    const int Mtot = nbat * TT;
    const int total4 = (int)(nbat * nb / 4);

    conv_add_kernel<<<total4 / 256, 256, 0, stream>>>(xb, Wc, xm, total4);

    {  // u = act(xm @ Wp^T): M=Mtot, N=4096, K=1024
      const int MB = Mtot / 256;
      const int nwg = MB * (4 * DD / 128);
      gemm256x128_kernel<1><<<nwg, 256, 0, stream>>>(xm, Wpb, u, Mtot, 4 * DD,
                                                     DD, MB);
    }
    {
      int nthreads = nbat * nchunk * (DD / 8);
      scan_chunk_kernel<<<nthreads / 256, 256, 0, stream>>>(u, cA, cB, nchunk,
                                                            tchunk);
      scan_prefix_kernel<<<(nbat * DD) / 256, 256, 0, stream>>>(cA, cB, S,
                                                                nchunk);
      scan_out_kernel<<<nthreads / 256, 256, 0, stream>>>(u, S, y, nchunk,
                                                          tchunk);
    }
    if (haveWob) {  // out = y @ Wo^T: M=Mtot, N=1024, K=1024
      const int MB = Mtot / 256;
      const int nwg = MB * (DD / 128);
      gemm256x128_kernel<0><<<nwg, 256, 0, stream>>>(y, Wob, outb, Mtot, DD,
                                                     DD, MB);
    } else {
      dim3 grid(DD / BN, Mtot / BM);
      gemm_nt_kernel<<<grid, 256, 0, stream>>>(y, Wo, outb, Mtot, DD, DD);
    }
  }
}